// Round 3
// baseline (1911.612 us; speedup 1.0000x reference)
//
#include <hip/hip_runtime.h>
#include <hip/hip_bf16.h>
#include <hip/hip_fp16.h>

typedef unsigned short u16;
typedef unsigned int u32;
typedef __attribute__((ext_vector_type(8))) _Float16 f16x8;
typedef __attribute__((ext_vector_type(4))) float f32x4;

#define RSTR 36          // red stride in floats (16B-aligned, 32 partials + pad)

__device__ __forceinline__ float bf2f(u16 b) {
  union { u32 u; float f; } c; c.u = ((u32)b) << 16; return c.f;
}
__device__ __forceinline__ u16 f2bf(float f) {
  union { float f; u32 u; } c; c.f = f;
  u32 r = c.u + 0x7FFFu + ((c.u >> 16) & 1u);
  return (u16)(r >> 16);
}
__device__ __forceinline__ float gelu_tanh(float x) {
  // tanh-form gelu == x * sigmoid(2*0.79788456*(x + 0.044715 x^3))
  float x2 = x * x;
  float t = __builtin_fmaf(0.044715f, x2, 1.0f);
  float e = __expf(-1.5957691216057308f * (x * t));
  return x * __builtin_amdgcn_rcpf(1.f + e);
}
// load a scalar param that may be fp32 or bf16
__device__ __forceinline__ float ldp(const void* p, int i, int f32) {
  return f32 ? ((const float*)p)[i] : bf2f(((const u16*)p)[i]);
}
// load 4 consecutive params (fp32 or bf16) vectorized
__device__ __forceinline__ f32x4 load4p(const void* p, int i, int f32) {
  if (f32) return *(const f32x4*)((const float*)p + i);
  ushort4 u = *(const ushort4*)((const u16*)p + i);
  return (f32x4){bf2f(u.x), bf2f(u.y), bf2f(u.z), bf2f(u.w)};
}
// load 8 consecutive elements (fp32 or bf16) as f16x8 (vectorized)
__device__ __forceinline__ f16x8 load8(const void* base, long off, int f32) {
  f16x8 r;
  if (f32) {
    const float4* p = (const float4*)((const float*)base + off);
    float4 a = p[0], b = p[1];
    r[0] = (_Float16)a.x; r[1] = (_Float16)a.y; r[2] = (_Float16)a.z; r[3] = (_Float16)a.w;
    r[4] = (_Float16)b.x; r[5] = (_Float16)b.y; r[6] = (_Float16)b.z; r[7] = (_Float16)b.w;
  } else {
    const u16* p = (const u16*)base + off;
#pragma unroll
    for (int i = 0; i < 8; ++i) r[i] = (_Float16)bf2f(p[i]);
  }
  return r;
}
// monotone (sortable) encoding of fp16 bit patterns, and decode-to-f32
__device__ __forceinline__ u32 encH(u32 h) {
  return (h & 0x8000u) ? (h ^ 0xFFFFu) : (h | 0x8000u);
}
__device__ __forceinline__ float decE(u32 e) {
  u32 h = (e & 0x8000u) ? (e & 0x7FFFu) : (~e & 0xFFFFu);
  return __half2float(__ushort_as_half((u16)h));
}
__device__ __forceinline__ u32 umin32(u32 a, u32 b) { return a < b ? a : b; }
__device__ __forceinline__ u32 umax32(u32 a, u32 b) { return a > b ? a : b; }

// one wave: decide whether inputs are fp32 (flag=1) or bf16 (flag=0).
__global__ void detect_dtype(const u16* __restrict__ obs, int* flag) {
  int l = threadIdx.x;
  float v = fabsf(bf2f(obs[2 * l]));
  if (v != v) v = 1e30f;  // NaN pattern also implies fp32
#pragma unroll
  for (int m = 1; m <= 32; m <<= 1) v = fmaxf(v, __shfl_xor(v, m, 64));
  if (l == 0) *flag = (v > 1000.0f) ? 1 : 0;
}

// Pack W [K x 512] into MFMA-fragment-major order (fp16):
// dst[((w*4+ci)*nk + t)*512 + lane*8 + j] = W[k][ch],
//   ch = w*64 + ci*16 + (lane&15), k = t*32 + (lane>>4)*8 + j.
__global__ void pack_frag(const void* __restrict__ src, u16* __restrict__ dst,
                          const int* __restrict__ flag, int total,
                          int fshift, int cishift, int tmask) {
  int id = blockIdx.x * 256 + threadIdx.x;
  if (id >= total) return;
  int j = id & 7;
  int lane = (id >> 3) & 63;
  int fi = id >> 9;
  int w = fi >> fshift;
  int rem = fi & ((1 << fshift) - 1);
  int ci = rem >> cishift;
  int t = rem & tmask;
  int q = lane >> 4, r = lane & 15;
  int ch = w * 64 + ci * 16 + r;
  int k = t * 32 + q * 8 + j;
  float v = ldp(src, k * 512 + ch, *flag);
  dst[id] = __half_as_ushort(__float2half(v));
}

// 16 waves x 1024 threads; each wave owns 32 output channels for 64 rows.
// acc[2][4] = 32 AGPRs/wave -> spill-free under the 128-reg/wave cap.
__global__ __launch_bounds__(1024, 4) void gciqe_main(
    const void* __restrict__ obs, const void* __restrict__ goals,
    const u16* __restrict__ wT0, const u16* __restrict__ wT1,
    const u16* __restrict__ wT2, const u16* __restrict__ wT3,
    const void* __restrict__ b0p, const void* __restrict__ b1p,
    const void* __restrict__ b2p, const void* __restrict__ b3p,
    const void* __restrict__ ls0, const void* __restrict__ lb0,
    const void* __restrict__ ls1, const void* __restrict__ lb1,
    const void* __restrict__ ls2, const void* __restrict__ lb2,
    const void* __restrict__ alphap, void* __restrict__ out,
    const int* __restrict__ flagp)
{
  // frag-major activation slab for layers 0..2 output (64 frags x 512 u16);
  // aliased as row-major [64][512] phi storage at l==3 (barrier-separated).
  __shared__ __align__(16) u16 slab[64 * 512];
  __shared__ __align__(16) float red[64 * RSTR];  // LN partials [row][wave]{s,t}

  const int f32 = *flagp;
  const int tid = threadIdx.x;
  const int lane = tid & 63, w2 = tid >> 6;     // 16 waves = 16 groups of 32 ch
  const int r = lane & 15, q = lane >> 4;
  const int i0 = blockIdx.x * 32;               // 32 pairs per block

  f32x4 acc[2][4];                              // [cj: 16-ch group][nt: row quarter]

  // ---------------- layer 0: [64 x 64] @ W0 -> acc ----------------
#pragma unroll
  for (int cj = 0; cj < 2; ++cj)
#pragma unroll
    for (int nt = 0; nt < 4; ++nt)
      acc[cj][nt] = (f32x4){0.f, 0.f, 0.f, 0.f};
  {
    f16x8 bf0[4][2];
#pragma unroll
    for (int nt = 0; nt < 4; ++nt) {
      int row = nt * 16 + r;                    // even = obs, odd = goals
      const void* base = (row & 1) ? goals : obs;
      long ro = (long)(i0 + (row >> 1)) * 64;
#pragma unroll
      for (int u = 0; u < 2; ++u)
        bf0[nt][u] = load8(base, ro + u * 32 + q * 8, f32);
    }
    // layer0 frag (w2,cj,t) at wT0 + (w2*4 + cj*2 + t)*512
    const u16* w0base = wT0 + w2 * 2048;
#pragma unroll
    for (int cj = 0; cj < 2; ++cj)
#pragma unroll
      for (int u = 0; u < 2; ++u) {
        f16x8 af = *(const f16x8*)(w0base + (cj * 2 + u) * 512 + lane * 8);
#pragma unroll
        for (int nt = 0; nt < 4; ++nt)
          acc[cj][nt] = __builtin_amdgcn_mfma_f32_16x16x32_f16(af, bf0[nt][u], acc[cj][nt], 0, 0, 0);
      }
  }

  // ---------------- layers 0..2 epilogue + layers 1..3 GEMM ----------------
  for (int l = 0; l <= 3; ++l) {
    if (l > 0) {
      const u16* wp = (l == 1) ? wT1 : (l == 2) ? wT2 : wT3;
      // frag (w2,cj,t) at wp + w2*16384 + cj*8192 + t*512
      const u16* wbase = wp + w2 * 16384;
#pragma unroll
      for (int cj = 0; cj < 2; ++cj)
#pragma unroll
        for (int nt = 0; nt < 4; ++nt)
          acc[cj][nt] = (f32x4){0.f, 0.f, 0.f, 0.f};
      // A-frag ring (2 ahead); step s = t*2 + cj
      f16x8 A[3];
      A[0] = *(const f16x8*)(wbase + lane * 8);           // s=0: cj0,t0
      A[1] = *(const f16x8*)(wbase + 8192 + lane * 8);    // s=1: cj1,t0
#pragma unroll
      for (int t = 0; t < 16; ++t) {
        // frag-major slab reads: linear lane*16B, conflict-free, imm offsets
        f16x8 B0 = *(const f16x8*)(slab + (0 * 16 + t) * 512 + lane * 8);
        f16x8 B1 = *(const f16x8*)(slab + (1 * 16 + t) * 512 + lane * 8);
        f16x8 B2 = *(const f16x8*)(slab + (2 * 16 + t) * 512 + lane * 8);
        f16x8 B3 = *(const f16x8*)(slab + (3 * 16 + t) * 512 + lane * 8);
#pragma unroll
        for (int cj = 0; cj < 2; ++cj) {
          const int s = t * 2 + cj;
          if (s + 2 < 32) {
            const int s2 = s + 2;
            A[s2 % 3] = *(const f16x8*)(wbase + (s2 & 1) * 8192 + (s2 >> 1) * 512 + lane * 8);
          }
          const f16x8 af = A[s % 3];
          acc[cj][0] = __builtin_amdgcn_mfma_f32_16x16x32_f16(af, B0, acc[cj][0], 0, 0, 0);
          acc[cj][1] = __builtin_amdgcn_mfma_f32_16x16x32_f16(af, B1, acc[cj][1], 0, 0, 0);
          acc[cj][2] = __builtin_amdgcn_mfma_f32_16x16x32_f16(af, B2, acc[cj][2], 0, 0, 0);
          acc[cj][3] = __builtin_amdgcn_mfma_f32_16x16x32_f16(af, B3, acc[cj][3], 0, 0, 0);
        }
      }
    }

    if (l < 3) {
      // ---- bias + gelu + LayerNorm -> frag-major slab (fp16) ----
      const void* pb  = (l == 0) ? b0p : (l == 1) ? b1p : b2p;
      const void* psl = (l == 0) ? ls0 : (l == 1) ? ls1 : ls2;
      const void* plb = (l == 0) ? lb0 : (l == 1) ? lb1 : lb2;
      float s_[4] = {0.f, 0.f, 0.f, 0.f}, t_[4] = {0.f, 0.f, 0.f, 0.f};
#pragma unroll
      for (int cj = 0; cj < 2; ++cj) {
        int cb = w2 * 32 + cj * 16 + q * 4;
        f32x4 bb = load4p(pb, cb, f32);
#pragma unroll
        for (int nt = 0; nt < 4; ++nt) {
          f32x4 v = acc[cj][nt];
          v.x = gelu_tanh(v.x + bb.x); v.y = gelu_tanh(v.y + bb.y);
          v.z = gelu_tanh(v.z + bb.z); v.w = gelu_tanh(v.w + bb.w);
          acc[cj][nt] = v;
          s_[nt] += v.x + v.y + v.z + v.w;
          t_[nt] += v.x * v.x + v.y * v.y + v.z * v.z + v.w * v.w;
        }
      }
#pragma unroll
      for (int nt = 0; nt < 4; ++nt) {
        s_[nt] += __shfl_xor(s_[nt], 16, 64); t_[nt] += __shfl_xor(t_[nt], 16, 64);
        s_[nt] += __shfl_xor(s_[nt], 32, 64); t_[nt] += __shfl_xor(t_[nt], 32, 64);
      }
      if (q == 0) {
#pragma unroll
        for (int nt = 0; nt < 4; ++nt)
          *(float2*)(red + (nt * 16 + r) * RSTR + w2 * 2) = make_float2(s_[nt], t_[nt]);
      }
      __syncthreads();   // also orders slab reads (GEMM) before slab writes below
      float mean[4], rstd[4];
#pragma unroll
      for (int nt = 0; nt < 4; ++nt) {
        int row = nt * 16 + r;
        float ts = 0.f, tq = 0.f;
#pragma unroll
        for (int p = 0; p < 8; ++p) {
          f32x4 a = *(const f32x4*)(red + row * RSTR + p * 4);
          ts += a.x + a.z; tq += a.y + a.w;
        }
        mean[nt] = ts * (1.f / 512.f);
        rstd[nt] = rsqrtf(tq * (1.f / 512.f) - mean[nt] * mean[nt] + 1e-6f);
      }
#pragma unroll
      for (int cj = 0; cj < 2; ++cj) {
        int cb = w2 * 32 + cj * 16 + q * 4;
        f32x4 gg = load4p(psl, cb, f32);
        f32x4 hh = load4p(plb, cb, f32);
        // frag-major destination: channel block lies in k-frag t = w2,
        // sub-offset (cj*2 + (q>>1))*128 + r*8 + (q&1)*4
        int sub = (cj * 2 + (q >> 1)) * 128 + r * 8 + (q & 1) * 4;
#pragma unroll
        for (int nt = 0; nt < 4; ++nt) {
          f32x4 v = acc[cj][nt];
          ushort4 o;
          o.x = __half_as_ushort(__float2half((v.x - mean[nt]) * rstd[nt] * gg.x + hh.x));
          o.y = __half_as_ushort(__float2half((v.y - mean[nt]) * rstd[nt] * gg.y + hh.y));
          o.z = __half_as_ushort(__float2half((v.z - mean[nt]) * rstd[nt] * gg.z + hh.z));
          o.w = __half_as_ushort(__float2half((v.w - mean[nt]) * rstd[nt] * gg.w + hh.w));
          *(ushort4*)(slab + (nt * 16 + w2) * 512 + sub) = o;
        }
      }
      __syncthreads();
    } else {
      // ---- layer 3: bias only; store phi row-major (aliases frag slab) ----
      __syncthreads();   // all waves done GEMM-reading frag slab before overwrite
#pragma unroll
      for (int cj = 0; cj < 2; ++cj) {
        int cb = w2 * 32 + cj * 16 + q * 4;
        f32x4 bb = load4p(b3p, cb, f32);
#pragma unroll
        for (int nt = 0; nt < 4; ++nt) {
          int row = nt * 16 + r;
          f32x4 v = acc[cj][nt];
          ushort4 o;
          o.x = __half_as_ushort(__float2half(v.x + bb.x));
          o.y = __half_as_ushort(__float2half(v.y + bb.y));
          o.z = __half_as_ushort(__float2half(v.z + bb.z));
          o.w = __half_as_ushort(__float2half(v.w + bb.w));
          *(ushort4*)(slab + row * 512 + cb) = o;
        }
      }
      __syncthreads();
    }
  }

  // ---------------- IQE head (packed u32 key|payload bitonic) ----------------
  {
    const float al = ldp(alphap, 0, f32);
    const float aa = 1.f / (1.f + __expf(-al));
    const int h = lane >> 5, il = lane & 31;    // two components per wave pass
#pragma unroll
    for (int pv = 0; pv < 2; ++pv) {
      int pL = 2 * w2 + pv;                     // block-local pair 0..31
      float cs = 0.f, cm = 0.f;
      for (int it = 0; it < 8; ++it) {
        int c = 2 * it + h;                     // component 0..15
        u32 xh = slab[(2 * pL) * 512 + c * 32 + il];
        u32 yh = slab[(2 * pL + 1) * 512 + c * 32 + il];
        u32 ex = encH(xh), ey = encH(yh);
        // invalid interval (!(x<y)) -> y = -inf encoding (0x03FF)
        u32 sv = (ex << 16) | ((ex < ey) ? ey : 0x03FFu);
        // bitonic ascending sort of packed (x|y) across each 32-lane half
#pragma unroll
        for (int k = 2; k <= 32; k <<= 1)
#pragma unroll
          for (int j = k >> 1; j >= 1; j >>= 1) {
            u32 so = __shfl_xor(sv, j, 64);
            u32 mn = umin32(sv, so), mx = umax32(sv, so);
            bool up = ((il & k) == 0) == ((il & j) == 0);
            sv = up ? mn : mx;
          }
        // exclusive prefix-max of encoded y in start-sorted order
        u32 ye = sv & 0xFFFFu;
        u32 p = __shfl_up(ye, 1, 32);
        if (il == 0) p = 0u;
#pragma unroll
        for (int d = 1; d <= 16; d <<= 1) {
          u32 t2 = __shfl_up(p, d, 32);
          if (il >= d) p = umax32(p, t2);
        }
        float contrib = fmaxf(0.f, decE(ye) - decE(umax32(sv >> 16, p)));
#pragma unroll
        for (int msk = 1; msk <= 16; msk <<= 1)
          contrib += __shfl_xor(contrib, msk, 64);
        cs += contrib;
        cm = fmaxf(cm, contrib);
      }
      cs += __shfl_xor(cs, 32, 64);
      cm = fmaxf(cm, __shfl_xor(cm, 32, 64));
      if (lane == 0) {
        float res = aa * (cs * (1.f / 16.f)) + (1.f - aa) * cm;
        if (f32) ((float*)out)[i0 + pL] = res;
        else ((u16*)out)[i0 + pL] = f2bf(res);
      }
    }
  }
}

extern "C" void kernel_launch(void* const* d_in, const int* in_sizes, int n_in,
                              void* d_out, int out_size, void* d_ws, size_t ws_size,
                              hipStream_t stream) {
  (void)in_sizes; (void)n_in; (void)out_size; (void)ws_size;
  const void* obs   = d_in[0];
  const void* goals = d_in[1];
  const void* W0 = d_in[2];
  const void* b0 = d_in[3];
  const void* ls0 = d_in[4];
  const void* lb0 = d_in[5];
  const void* W1 = d_in[6];
  const void* b1 = d_in[7];
  const void* ls1 = d_in[8];
  const void* lb1 = d_in[9];
  const void* W2 = d_in[10];
  const void* b2 = d_in[11];
  const void* ls2 = d_in[12];
  const void* lb2 = d_in[13];
  const void* W3 = d_in[14];
  const void* b3 = d_in[15];
  const void* alpha = d_in[16];

  int* flag = (int*)d_ws;
  u16* wT0 = (u16*)((char*)d_ws + 64);
  u16* wT1 = wT0 + 512 * 64;
  u16* wT2 = wT1 + 512 * 512;
  u16* wT3 = wT2 + 512 * 512;

  detect_dtype<<<1, 64, 0, stream>>>((const u16*)obs, flag);
  // layer0: K=64, nk=2: fshift=3 (4*nk=8 frags/wave), cishift=1, tmask=1
  pack_frag<<<128, 256, 0, stream>>>(W0, wT0, flag, 512 * 64, 3, 1, 1);
  // layers1-3: K=512, nk=16: fshift=6 (64 frags/wave), cishift=4, tmask=15
  pack_frag<<<1024, 256, 0, stream>>>(W1, wT1, flag, 512 * 512, 6, 4, 15);
  pack_frag<<<1024, 256, 0, stream>>>(W2, wT2, flag, 512 * 512, 6, 4, 15);
  pack_frag<<<1024, 256, 0, stream>>>(W3, wT3, flag, 512 * 512, 6, 4, 15);
  // 131072 pairs / 32 pairs-per-block = 4096 blocks (round-2 bug: was 2048)
  gciqe_main<<<4096, 1024, 0, stream>>>(obs, goals, wT0, wT1, wT2, wT3,
      b0, b1, b2, b3, ls0, lb0, ls1, lb1, ls2, lb2, alpha, d_out, flag);
}

// Round 4
// 983.850 us; speedup vs baseline: 1.9430x; 1.9430x over previous
//
#include <hip/hip_runtime.h>
#include <hip/hip_bf16.h>
#include <hip/hip_fp16.h>

typedef unsigned short u16;
typedef unsigned int u32;
typedef __attribute__((ext_vector_type(8))) _Float16 f16x8;
typedef __attribute__((ext_vector_type(4))) float f32x4;

#define ROWS 32          // 16 s/g pairs per block
#define SSTR 520         // slab stride in u16
#define RSTR 20          // red stride in floats (16B-aligned, bank-spread)

__device__ __forceinline__ float bf2f(u16 b) {
  union { u32 u; float f; } c; c.u = ((u32)b) << 16; return c.f;
}
__device__ __forceinline__ u16 f2bf(float f) {
  union { float f; u32 u; } c; c.f = f;
  u32 r = c.u + 0x7FFFu + ((c.u >> 16) & 1u);
  return (u16)(r >> 16);
}
__device__ __forceinline__ float gelu_tanh(float x) {
  // tanh-form gelu == x * sigmoid(2*0.79788456*(x + 0.044715 x^3))
  float x2 = x * x;
  float t = __builtin_fmaf(0.044715f, x2, 1.0f);
  float e = __expf(-1.5957691216057308f * (x * t));
  return x * __builtin_amdgcn_rcpf(1.f + e);
}
// load a scalar param that may be fp32 or bf16
__device__ __forceinline__ float ldp(const void* p, int i, int f32) {
  return f32 ? ((const float*)p)[i] : bf2f(((const u16*)p)[i]);
}
// load 4 consecutive params (fp32 or bf16) vectorized
__device__ __forceinline__ f32x4 load4p(const void* p, int i, int f32) {
  if (f32) return *(const f32x4*)((const float*)p + i);
  ushort4 u = *(const ushort4*)((const u16*)p + i);
  return (f32x4){bf2f(u.x), bf2f(u.y), bf2f(u.z), bf2f(u.w)};
}
// load 8 consecutive elements (fp32 or bf16) as f16x8 (vectorized)
__device__ __forceinline__ f16x8 load8(const void* base, long off, int f32) {
  f16x8 r;
  if (f32) {
    const float4* p = (const float4*)((const float*)base + off);
    float4 a = p[0], b = p[1];
    r[0] = (_Float16)a.x; r[1] = (_Float16)a.y; r[2] = (_Float16)a.z; r[3] = (_Float16)a.w;
    r[4] = (_Float16)b.x; r[5] = (_Float16)b.y; r[6] = (_Float16)b.z; r[7] = (_Float16)b.w;
  } else {
    const u16* p = (const u16*)base + off;
#pragma unroll
    for (int i = 0; i < 8; ++i) r[i] = (_Float16)bf2f(p[i]);
  }
  return r;
}
// monotone (sortable) encoding of fp16 bit patterns, and decode-to-f32
__device__ __forceinline__ u32 encH(u32 h) {
  return (h & 0x8000u) ? (h ^ 0xFFFFu) : (h | 0x8000u);
}
__device__ __forceinline__ float decE(u32 e) {
  u32 h = (e & 0x8000u) ? (e & 0x7FFFu) : (~e & 0xFFFFu);
  return __half2float(__ushort_as_half((u16)h));
}
__device__ __forceinline__ u32 umin32(u32 a, u32 b) { return a < b ? a : b; }
__device__ __forceinline__ u32 umax32(u32 a, u32 b) { return a > b ? a : b; }

// one wave: decide whether inputs are fp32 (flag=1) or bf16 (flag=0).
__global__ void detect_dtype(const u16* __restrict__ obs, int* flag) {
  int l = threadIdx.x;
  float v = fabsf(bf2f(obs[2 * l]));
  if (v != v) v = 1e30f;  // NaN pattern also implies fp32
#pragma unroll
  for (int m = 1; m <= 32; m <<= 1) v = fmaxf(v, __shfl_xor(v, m, 64));
  if (l == 0) *flag = (v > 1000.0f) ? 1 : 0;
}

// Pack W [K x 512] into MFMA-fragment-major order (fp16):
// dst[((w*4+ci)*nk + t)*512 + lane*8 + j] = W[k][ch],
//   ch = w*64 + ci*16 + (lane&15), k = t*32 + (lane>>4)*8 + j.
__global__ void pack_frag(const void* __restrict__ src, u16* __restrict__ dst,
                          const int* __restrict__ flag, int total,
                          int fshift, int cishift, int tmask) {
  int id = blockIdx.x * 256 + threadIdx.x;
  if (id >= total) return;
  int j = id & 7;
  int lane = (id >> 3) & 63;
  int fi = id >> 9;
  int w = fi >> fshift;
  int rem = fi & ((1 << fshift) - 1);
  int ci = rem >> cishift;
  int t = rem & tmask;
  int q = lane >> 4, r = lane & 15;
  int ch = w * 64 + ci * 16 + r;
  int k = t * 32 + q * 8 + j;
  float v = ldp(src, k * 512 + ch, *flag);
  dst[id] = __half_as_ushort(__float2half(v));
}

__global__ __launch_bounds__(512, 4) void gciqe_main(
    const void* __restrict__ obs, const void* __restrict__ goals,
    const u16* __restrict__ wT0, const u16* __restrict__ wT1,
    const u16* __restrict__ wT2, const u16* __restrict__ wT3,
    const void* __restrict__ b0, const void* __restrict__ b1,
    const void* __restrict__ b2, const void* __restrict__ b3,
    const void* __restrict__ ls0, const void* __restrict__ lb0,
    const void* __restrict__ ls1, const void* __restrict__ lb1,
    const void* __restrict__ ls2, const void* __restrict__ lb2,
    const void* __restrict__ alphap, void* __restrict__ out,
    const int* __restrict__ flagp)
{
  __shared__ __align__(16) u16 slab[ROWS * SSTR];   // activations / phi, fp16 bits
  __shared__ __align__(16) float red[ROWS * RSTR];  // LN partials [row][wave]{s,t}

  const int f32 = *flagp;
  const int tid = threadIdx.x;
  const int lane = tid & 63, w = tid >> 6;      // 8 waves = 8 groups of 64 ch
  const int r = lane & 15, q = lane >> 4;
  const int i0 = blockIdx.x * 16;               // 16 pairs per block

  f32x4 acc[4][2];                              // [ci: 16-ch group][nt: row half]

  // ---------------- layer 0: [32 x 64] @ W0 -> acc ----------------
#pragma unroll
  for (int ci = 0; ci < 4; ++ci) {
    acc[ci][0] = (f32x4){0.f, 0.f, 0.f, 0.f};
    acc[ci][1] = (f32x4){0.f, 0.f, 0.f, 0.f};
  }
  {
    f16x8 bf0[2][2];
#pragma unroll
    for (int nt = 0; nt < 2; ++nt) {
      int row = nt * 16 + r;                    // even = obs, odd = goals
      const void* base = (row & 1) ? goals : obs;
      long ro = (long)(i0 + (row >> 1)) * 64;
#pragma unroll
      for (int u = 0; u < 2; ++u)
        bf0[nt][u] = load8(base, ro + u * 32 + q * 8, f32);
    }
    const u16* w0base = wT0 + w * 4096;         // 8 frags of 512 u16 per wave
#pragma unroll
    for (int ci = 0; ci < 4; ++ci) {
#pragma unroll
      for (int u = 0; u < 2; ++u) {
        f16x8 af = *(const f16x8*)(w0base + (ci * 2 + u) * 512 + lane * 8);
        acc[ci][0] = __builtin_amdgcn_mfma_f32_16x16x32_f16(af, bf0[0][u], acc[ci][0], 0, 0, 0);
        acc[ci][1] = __builtin_amdgcn_mfma_f32_16x16x32_f16(af, bf0[1][u], acc[ci][1], 0, 0, 0);
      }
    }
  }

  // ---------------- layers 0..2 epilogue + layers 1..3 GEMM ----------------
  for (int l = 0; l <= 3; ++l) {
    if (l > 0) {
      const u16* wp = (l == 1) ? wT1 : (l == 2) ? wT2 : wT3;
      const u16* wbase = wp + w * 32768;        // 64 frags of 512 u16 per wave
#pragma unroll
      for (int ci = 0; ci < 4; ++ci) {
        acc[ci][0] = (f32x4){0.f, 0.f, 0.f, 0.f};
        acc[ci][1] = (f32x4){0.f, 0.f, 0.f, 0.f};
      }
      // register double-buffer over (kq,ci) steps; frag f = ci*16 + kq*4 + u
      f16x8 A[2][4];
#pragma unroll
      for (int u = 0; u < 4; ++u)
        A[0][u] = *(const f16x8*)(wbase + u * 512 + lane * 8);   // ci=0,kq=0
#pragma unroll
      for (int kq = 0; kq < 4; ++kq) {          // K in chunks of 128
        f16x8 bfr[2][4];
#pragma unroll
        for (int nt = 0; nt < 2; ++nt)
#pragma unroll
          for (int u = 0; u < 4; ++u)
            bfr[nt][u] = *(const f16x8*)(slab + (nt * 16 + r) * SSTR + kq * 128 + u * 32 + q * 8);
#pragma unroll
        for (int ci = 0; ci < 4; ++ci) {
          const int step = kq * 4 + ci;
          const int cur = step & 1;
          if (step < 15) {
            const int nstep = step + 1;
            const int nci = nstep & 3, nkq = nstep >> 2;
#pragma unroll
            for (int u = 0; u < 4; ++u)
              A[cur ^ 1][u] = *(const f16x8*)(wbase + (nci * 16 + nkq * 4 + u) * 512 + lane * 8);
          }
#pragma unroll
          for (int u = 0; u < 4; ++u) {
            acc[ci][0] = __builtin_amdgcn_mfma_f32_16x16x32_f16(A[cur][u], bfr[0][u], acc[ci][0], 0, 0, 0);
            acc[ci][1] = __builtin_amdgcn_mfma_f32_16x16x32_f16(A[cur][u], bfr[1][u], acc[ci][1], 0, 0, 0);
          }
        }
      }
    }

    if (l < 3) {
      // ---- bias + gelu + LayerNorm -> slab (fp16) ----
      const void* pb  = (l == 0) ? b0 : (l == 1) ? b1 : b2;
      const void* psl = (l == 0) ? ls0 : (l == 1) ? ls1 : ls2;
      const void* plb = (l == 0) ? lb0 : (l == 1) ? lb1 : lb2;
      float s[2] = {0.f, 0.f}, t[2] = {0.f, 0.f};
#pragma unroll
      for (int ci = 0; ci < 4; ++ci) {
        int cb = w * 64 + ci * 16 + q * 4;
        f32x4 bb = load4p(pb, cb, f32);
#pragma unroll
        for (int nt = 0; nt < 2; ++nt) {
          f32x4 v = acc[ci][nt];
          v.x = gelu_tanh(v.x + bb.x); v.y = gelu_tanh(v.y + bb.y);
          v.z = gelu_tanh(v.z + bb.z); v.w = gelu_tanh(v.w + bb.w);
          acc[ci][nt] = v;
          s[nt] += v.x + v.y + v.z + v.w;
          t[nt] += v.x * v.x + v.y * v.y + v.z * v.z + v.w * v.w;
        }
      }
#pragma unroll
      for (int nt = 0; nt < 2; ++nt) {
        s[nt] += __shfl_xor(s[nt], 16, 64); t[nt] += __shfl_xor(t[nt], 16, 64);
        s[nt] += __shfl_xor(s[nt], 32, 64); t[nt] += __shfl_xor(t[nt], 32, 64);
      }
      if (q == 0) {
        *(float2*)(red + (0 * 16 + r) * RSTR + w * 2) = make_float2(s[0], t[0]);
        *(float2*)(red + (1 * 16 + r) * RSTR + w * 2) = make_float2(s[1], t[1]);
      }
      __syncthreads();   // also orders slab reads (GEMM) before slab writes below
      float mean[2], rstd[2];
#pragma unroll
      for (int nt = 0; nt < 2; ++nt) {
        int row = nt * 16 + r;
        float ts = 0.f, tq = 0.f;
#pragma unroll
        for (int p = 0; p < 4; ++p) {
          f32x4 a = *(const f32x4*)(red + row * RSTR + p * 4);
          ts += a.x + a.z; tq += a.y + a.w;
        }
        mean[nt] = ts * (1.f / 512.f);
        rstd[nt] = rsqrtf(tq * (1.f / 512.f) - mean[nt] * mean[nt] + 1e-6f);
      }
#pragma unroll
      for (int ci = 0; ci < 4; ++ci) {
        int cb = w * 64 + ci * 16 + q * 4;
        f32x4 gg = load4p(psl, cb, f32);
        f32x4 hh = load4p(plb, cb, f32);
#pragma unroll
        for (int nt = 0; nt < 2; ++nt) {
          int row = nt * 16 + r;
          f32x4 v = acc[ci][nt];
          ushort4 o;
          o.x = __half_as_ushort(__float2half((v.x - mean[nt]) * rstd[nt] * gg.x + hh.x));
          o.y = __half_as_ushort(__float2half((v.y - mean[nt]) * rstd[nt] * gg.y + hh.y));
          o.z = __half_as_ushort(__float2half((v.z - mean[nt]) * rstd[nt] * gg.z + hh.z));
          o.w = __half_as_ushort(__float2half((v.w - mean[nt]) * rstd[nt] * gg.w + hh.w));
          *(ushort4*)(slab + row * SSTR + cb) = o;
        }
      }
      __syncthreads();
    } else {
      // ---- layer 3: bias only; store phi as fp16 ----
      __syncthreads();   // all waves done GEMM-reading slab before overwrite
#pragma unroll
      for (int ci = 0; ci < 4; ++ci) {
        int cb = w * 64 + ci * 16 + q * 4;
        f32x4 bb = load4p(b3, cb, f32);
#pragma unroll
        for (int nt = 0; nt < 2; ++nt) {
          int row = nt * 16 + r;
          f32x4 v = acc[ci][nt];
          ushort4 o;
          o.x = __half_as_ushort(__float2half(v.x + bb.x));
          o.y = __half_as_ushort(__float2half(v.y + bb.y));
          o.z = __half_as_ushort(__float2half(v.z + bb.z));
          o.w = __half_as_ushort(__float2half(v.w + bb.w));
          *(ushort4*)(slab + row * SSTR + cb) = o;
        }
      }
      __syncthreads();
    }
  }

  // ---------------- IQE head (packed u32 key|payload bitonic) ----------------
  {
    const float al = ldp(alphap, 0, f32);
    const float aa = 1.f / (1.f + __expf(-al));
    const int h = lane >> 5, il = lane & 31;    // two components per wave pass
#pragma unroll
    for (int pv = 0; pv < 2; ++pv) {
      int pL = 2 * w + pv;                      // block-local pair 0..15
      float cs = 0.f, cm = 0.f;
      for (int it = 0; it < 8; ++it) {
        int c = 2 * it + h;                     // component 0..15
        u32 xh = slab[(2 * pL) * SSTR + c * 32 + il];
        u32 yh = slab[(2 * pL + 1) * SSTR + c * 32 + il];
        u32 ex = encH(xh), ey = encH(yh);
        // invalid interval (!(x<y)) -> y = -inf encoding (0x03FF)
        u32 sv = (ex << 16) | ((ex < ey) ? ey : 0x03FFu);
        // bitonic ascending sort of packed (x|y) across each 32-lane half
#pragma unroll
        for (int k = 2; k <= 32; k <<= 1)
#pragma unroll
          for (int j = k >> 1; j >= 1; j >>= 1) {
            u32 so = __shfl_xor(sv, j, 64);
            u32 mn = umin32(sv, so), mx = umax32(sv, so);
            bool up = ((il & k) == 0) == ((il & j) == 0);
            sv = up ? mn : mx;
          }
        // exclusive prefix-max of encoded y in start-sorted order
        u32 ye = sv & 0xFFFFu;
        u32 p = __shfl_up(ye, 1, 32);
        if (il == 0) p = 0u;
#pragma unroll
        for (int d = 1; d <= 16; d <<= 1) {
          u32 t2 = __shfl_up(p, d, 32);
          if (il >= d) p = umax32(p, t2);
        }
        float contrib = fmaxf(0.f, decE(ye) - decE(umax32(sv >> 16, p)));
#pragma unroll
        for (int msk = 1; msk <= 16; msk <<= 1)
          contrib += __shfl_xor(contrib, msk, 64);
        cs += contrib;
        cm = fmaxf(cm, contrib);
      }
      cs += __shfl_xor(cs, 32, 64);
      cm = fmaxf(cm, __shfl_xor(cm, 32, 64));
      if (lane == 0) {
        float res = aa * (cs * (1.f / 16.f)) + (1.f - aa) * cm;
        if (f32) ((float*)out)[i0 + pL] = res;
        else ((u16*)out)[i0 + pL] = f2bf(res);
      }
    }
  }
}

extern "C" void kernel_launch(void* const* d_in, const int* in_sizes, int n_in,
                              void* d_out, int out_size, void* d_ws, size_t ws_size,
                              hipStream_t stream) {
  (void)in_sizes; (void)n_in; (void)out_size; (void)ws_size;
  const void* obs   = d_in[0];
  const void* goals = d_in[1];
  const void* W0 = d_in[2];
  const void* b0 = d_in[3];
  const void* ls0 = d_in[4];
  const void* lb0 = d_in[5];
  const void* W1 = d_in[6];
  const void* b1 = d_in[7];
  const void* ls1 = d_in[8];
  const void* lb1 = d_in[9];
  const void* W2 = d_in[10];
  const void* b2 = d_in[11];
  const void* ls2 = d_in[12];
  const void* lb2 = d_in[13];
  const void* W3 = d_in[14];
  const void* b3 = d_in[15];
  const void* alpha = d_in[16];

  int* flag = (int*)d_ws;
  u16* wT0 = (u16*)((char*)d_ws + 64);
  u16* wT1 = wT0 + 512 * 64;
  u16* wT2 = wT1 + 512 * 512;
  u16* wT3 = wT2 + 512 * 512;

  detect_dtype<<<1, 64, 0, stream>>>((const u16*)obs, flag);
  // layer0: K=64, nk=2: fshift=3 (4*nk=8 frags/wave), cishift=1, tmask=1
  pack_frag<<<128, 256, 0, stream>>>(W0, wT0, flag, 512 * 64, 3, 1, 1);
  // layers1-3: K=512, nk=16: fshift=6 (64 frags/wave), cishift=4, tmask=15
  pack_frag<<<1024, 256, 0, stream>>>(W1, wT1, flag, 512 * 512, 6, 4, 15);
  pack_frag<<<1024, 256, 0, stream>>>(W2, wT2, flag, 512 * 512, 6, 4, 15);
  pack_frag<<<1024, 256, 0, stream>>>(W3, wT3, flag, 512 * 512, 6, 4, 15);
  gciqe_main<<<8192, 512, 0, stream>>>(obs, goals, wT0, wT1, wT2, wT3,
      b0, b1, b2, b3, ls0, lb0, ls1, lb1, ls2, lb2, alpha, d_out, flag);
}